// Round 1
// baseline (776.979 us; speedup 1.0000x reference)
//
#include <hip/hip_runtime.h>
#include <hip/hip_bf16.h>
#include <math.h>

#define N_NODES 50000
#define N_EDGES 800000
#define ET      (N_EDGES + N_NODES)   // with self loops
#define IN_DIM  128
#define HEADS   4
#define HID     64
#define HC      256                   // HEADS*HID
#define OUTD    128

// ---------------- CSR build ----------------

__global__ void hist_k(const int* __restrict__ ei, int* __restrict__ counts) {
    int i = blockIdx.x * blockDim.x + threadIdx.x;
    if (i >= ET) return;
    int dv = (i < N_EDGES) ? ei[N_EDGES + i] : (i - N_EDGES);
    atomicAdd(&counts[dv], 1);
}

__global__ void scan1_k(const int* __restrict__ counts, int* __restrict__ offs,
                        int* __restrict__ bsums) {
    __shared__ int sm[512];
    int tid = threadIdx.x;
    int i = blockIdx.x * 512 + tid;
    int v = (i < N_NODES) ? counts[i] : 0;
    sm[tid] = v;
    __syncthreads();
    #pragma unroll
    for (int o = 1; o < 512; o <<= 1) {
        int add = (tid >= o) ? sm[tid - o] : 0;
        __syncthreads();
        sm[tid] += add;
        __syncthreads();
    }
    if (i < N_NODES) offs[i] = sm[tid] - v;        // exclusive
    if (tid == 511) bsums[blockIdx.x] = sm[511];
}

__global__ void scan2_k(int* __restrict__ bsums, int nb) {
    __shared__ int sm[128];
    int tid = threadIdx.x;
    int v = (tid < nb) ? bsums[tid] : 0;
    sm[tid] = v;
    __syncthreads();
    #pragma unroll
    for (int o = 1; o < 128; o <<= 1) {
        int add = (tid >= o) ? sm[tid - o] : 0;
        __syncthreads();
        sm[tid] += add;
        __syncthreads();
    }
    if (tid < nb) bsums[tid] = sm[tid] - v;        // exclusive
}

__global__ void scan3_k(int* __restrict__ offs, const int* __restrict__ bsums) {
    int i = blockIdx.x * 512 + threadIdx.x;
    if (i < N_NODES) offs[i] += bsums[blockIdx.x];
    if (i == 0) offs[N_NODES] = ET;
}

__global__ void fill_k(const int* __restrict__ ei, const int* __restrict__ offs,
                       int* __restrict__ cursor, int* __restrict__ csr) {
    int i = blockIdx.x * blockDim.x + threadIdx.x;
    if (i >= ET) return;
    int sv, dv;
    if (i < N_EDGES) { sv = ei[i]; dv = ei[N_EDGES + i]; }
    else             { sv = dv = i - N_EDGES; }
    int pos = offs[dv] + atomicAdd(&cursor[dv], 1);
    csr[pos] = sv;
}

// ---------------- GEMM (fp32, 64x64 tile, 256 thr, 4x4/thread) ----------------

__global__ __launch_bounds__(256) void gemm_k(const float* __restrict__ A,
                                              const float* __restrict__ B,
                                              float* __restrict__ C,
                                              int N, int K, int Mout) {
    __shared__ float As[16][68];
    __shared__ float Bs[16][68];
    int t = threadIdx.x;
    int row0 = blockIdx.x * 64;
    int col0 = blockIdx.y * 64;
    int ty = t >> 4, tx = t & 15;
    float acc[4][4];
    #pragma unroll
    for (int i = 0; i < 4; ++i)
        #pragma unroll
        for (int j = 0; j < 4; ++j) acc[i][j] = 0.f;

    int la_r = t >> 2;            // 0..63
    int la_k = (t & 3) * 4;       // 0,4,8,12
    int lb_k = t >> 4;            // 0..15
    int lb_n = (t & 15) * 4;      // 0..60

    for (int k0 = 0; k0 < K; k0 += 16) {
        float4 av = make_float4(0.f, 0.f, 0.f, 0.f);
        int ar = row0 + la_r;
        if (ar < N) av = *(const float4*)(A + (size_t)ar * K + k0 + la_k);
        float4 bv = *(const float4*)(B + (size_t)(k0 + lb_k) * Mout + col0 + lb_n);
        __syncthreads();
        As[la_k + 0][la_r] = av.x;
        As[la_k + 1][la_r] = av.y;
        As[la_k + 2][la_r] = av.z;
        As[la_k + 3][la_r] = av.w;
        *(float4*)&Bs[lb_k][lb_n] = bv;
        __syncthreads();
        #pragma unroll
        for (int kk = 0; kk < 16; ++kk) {
            float4 a = *(const float4*)&As[kk][ty * 4];
            float4 b = *(const float4*)&Bs[kk][tx * 4];
            acc[0][0] += a.x * b.x; acc[0][1] += a.x * b.y; acc[0][2] += a.x * b.z; acc[0][3] += a.x * b.w;
            acc[1][0] += a.y * b.x; acc[1][1] += a.y * b.y; acc[1][2] += a.y * b.z; acc[1][3] += a.y * b.w;
            acc[2][0] += a.z * b.x; acc[2][1] += a.z * b.y; acc[2][2] += a.z * b.z; acc[2][3] += a.z * b.w;
            acc[3][0] += a.w * b.x; acc[3][1] += a.w * b.y; acc[3][2] += a.w * b.z; acc[3][3] += a.w * b.w;
        }
    }
    #pragma unroll
    for (int i = 0; i < 4; ++i) {
        int r = row0 + ty * 4 + i;
        if (r < N)
            *(float4*)(C + (size_t)r * Mout + col0 + tx * 4) =
                make_float4(acc[i][0], acc[i][1], acc[i][2], acc[i][3]);
    }
}

// ---------------- per-node attention scores s,d ----------------

template<int H, int C>
__global__ __launch_bounds__(256) void scores_k(const float* __restrict__ xp,
                                                const float* __restrict__ asrc,
                                                const float* __restrict__ adst,
                                                float* __restrict__ s,
                                                float* __restrict__ d) {
    constexpr int HCl = H * C;
    constexpr int EPL = HCl / 64;
    int wid = blockIdx.x * 4 + (threadIdx.x >> 6);
    int lane = threadIdx.x & 63;
    if (wid >= N_NODES) return;
    const float* row = xp + (size_t)wid * HCl + lane * EPL;
    float ps = 0.f, pd = 0.f;
    #pragma unroll
    for (int k = 0; k < EPL; ++k) {
        float v = row[k];
        ps += v * asrc[lane * EPL + k];
        pd += v * adst[lane * EPL + k];
    }
    constexpr int GW = 64 / H;
    #pragma unroll
    for (int o = 1; o < GW; o <<= 1) {
        ps += __shfl_xor(ps, o, 64);
        pd += __shfl_xor(pd, o, 64);
    }
    if ((lane & (GW - 1)) == 0) {
        int h = lane / GW;
        s[(size_t)wid * H + h] = ps;
        d[(size_t)wid * H + h] = pd;
    }
}

// ---------------- per-dst-node online-softmax aggregation ----------------

template<int H, int C, bool ELU_OUT>
__global__ __launch_bounds__(256) void aggr_k(const float* __restrict__ xp,
                                              const float* __restrict__ s,
                                              const float* __restrict__ d,
                                              const int* __restrict__ offs,
                                              const int* __restrict__ csr,
                                              const float* __restrict__ bias,
                                              float* __restrict__ out) {
    constexpr int HCl = H * C;
    constexpr int EPL = HCl / 64;
    int wid = blockIdx.x * 4 + (threadIdx.x >> 6);
    int lane = threadIdx.x & 63;
    if (wid >= N_NODES) return;
    int h = (lane * EPL) / C;
    float dh = d[(size_t)wid * H + h];
    float m = -1e30f, z = 0.f;
    float acc[EPL];
    #pragma unroll
    for (int k = 0; k < EPL; ++k) acc[k] = 0.f;

    int e0 = offs[wid], e1 = offs[wid + 1];
    for (int j = e0; j < e1; ++j) {
        int src = csr[j];
        float e = s[(size_t)src * H + h] + dh;
        e = (e > 0.f) ? e : 0.2f * e;          // leaky_relu
        float mn = fmaxf(m, e);
        float sc = __expf(m - mn);
        float p  = __expf(e - mn);
        z = z * sc + p;
        const float* xr = xp + (size_t)src * HCl + lane * EPL;
        float v[EPL];
        if constexpr (EPL == 4) {
            float4 tv = *(const float4*)xr;
            v[0] = tv.x; v[1] = tv.y; v[2] = tv.z; v[3] = tv.w;
        } else {
            float2 tv = *(const float2*)xr;
            v[0] = tv.x; v[1] = tv.y;
        }
        #pragma unroll
        for (int k = 0; k < EPL; ++k) acc[k] = acc[k] * sc + p * v[k];
        m = mn;
    }
    float inv = 1.f / (z + 1e-16f);
    #pragma unroll
    for (int k = 0; k < EPL; ++k) {
        float o = acc[k] * inv + bias[lane * EPL + k];
        if constexpr (ELU_OUT) o = (o > 0.f) ? o : (__expf(o) - 1.f);
        out[(size_t)wid * HCl + lane * EPL + k] = o;
    }
}

// ---------------- launch ----------------

extern "C" void kernel_launch(void* const* d_in, const int* in_sizes, int n_in,
                              void* d_out, int out_size, void* d_ws, size_t ws_size,
                              hipStream_t stream) {
    const float* x      = (const float*)d_in[0];
    const int*   ei     = (const int*)  d_in[1];
    const float* W0     = (const float*)d_in[2];
    const float* as0    = (const float*)d_in[3];
    const float* ad0    = (const float*)d_in[4];
    const float* b0     = (const float*)d_in[5];
    const float* W1     = (const float*)d_in[6];
    const float* as1    = (const float*)d_in[7];
    const float* ad1    = (const float*)d_in[8];
    const float* b1     = (const float*)d_in[9];
    const float* W2     = (const float*)d_in[10];
    const float* as2    = (const float*)d_in[11];
    const float* ad2    = (const float*)d_in[12];
    const float* b2     = (const float*)d_in[13];
    float* out = (float*)d_out;

    // workspace layout (256B aligned chunks)
    char* p = (char*)d_ws;
    auto take = [&](size_t bytes) {
        char* r = p;
        p += (bytes + 255) & ~(size_t)255;
        return r;
    };
    float* XP     = (float*)take((size_t)N_NODES * HC * 4);
    float* Hbuf   = (float*)take((size_t)N_NODES * HC * 4);
    float* S      = (float*)take((size_t)N_NODES * HEADS * 4);
    float* D      = (float*)take((size_t)N_NODES * HEADS * 4);
    int*   counts = (int*)  take((size_t)2 * N_NODES * 4);   // counts + cursor contiguous
    int*   cursor = counts + N_NODES;
    int*   offs   = (int*)  take((size_t)(N_NODES + 1) * 4);
    int*   bsums  = (int*)  take(512 * 4);
    int*   csr    = (int*)  take((size_t)ET * 4);

    const int NB_SCAN = (N_NODES + 511) / 512;   // 98
    const int ET_BLOCKS = (ET + 255) / 256;
    const int NODE_BLOCKS = (N_NODES + 3) / 4;   // 12500

    // ---- CSR build ----
    hipMemsetAsync(counts, 0, (size_t)2 * N_NODES * 4, stream);
    hist_k<<<ET_BLOCKS, 256, 0, stream>>>(ei, counts);
    scan1_k<<<NB_SCAN, 512, 0, stream>>>(counts, offs, bsums);
    scan2_k<<<1, 128, 0, stream>>>(bsums, NB_SCAN);
    scan3_k<<<NB_SCAN, 512, 0, stream>>>(offs, bsums);
    fill_k<<<ET_BLOCKS, 256, 0, stream>>>(ei, offs, cursor, csr);

    dim3 g0((N_NODES + 63) / 64, HC / 64);
    dim3 g2((N_NODES + 63) / 64, OUTD / 64);

    // ---- layer 0: 128 -> 4x64, concat, ELU ----
    gemm_k<<<g0, 256, 0, stream>>>(x, W0, XP, N_NODES, IN_DIM, HC);
    scores_k<HEADS, HID><<<NODE_BLOCKS, 256, 0, stream>>>(XP, as0, ad0, S, D);
    aggr_k<HEADS, HID, true><<<NODE_BLOCKS, 256, 0, stream>>>(XP, S, D, offs, csr, b0, Hbuf);

    // ---- layer 1: 256 -> 4x64, concat, ELU ----
    gemm_k<<<g0, 256, 0, stream>>>(Hbuf, W1, XP, N_NODES, HC, HC);
    scores_k<HEADS, HID><<<NODE_BLOCKS, 256, 0, stream>>>(XP, as1, ad1, S, D);
    aggr_k<HEADS, HID, true><<<NODE_BLOCKS, 256, 0, stream>>>(XP, S, D, offs, csr, b1, Hbuf);

    // ---- layer 2: 256 -> 1x128, mean(H=1), no ELU ----
    gemm_k<<<g2, 256, 0, stream>>>(Hbuf, W2, XP, N_NODES, HC, OUTD);
    scores_k<1, OUTD><<<NODE_BLOCKS, 256, 0, stream>>>(XP, as2, ad2, S, D);
    aggr_k<1, OUTD, false><<<NODE_BLOCKS, 256, 0, stream>>>(XP, S, D, offs, csr, b2, out);
}

// Round 2
// 593.300 us; speedup vs baseline: 1.3096x; 1.3096x over previous
//
#include <hip/hip_runtime.h>
#include <hip/hip_bf16.h>
#include <hip/hip_fp16.h>
#include <math.h>

#define N_NODES 50000
#define N_EDGES 800000
#define ET      (N_EDGES + N_NODES)   // with self loops
#define IN_DIM  128
#define HEADS   4
#define HID     64
#define HC      256                   // HEADS*HID
#define OUTD    128

// ---------------- CSR build ----------------

__global__ void hist_k(const int* __restrict__ ei, int* __restrict__ counts) {
    int i = blockIdx.x * blockDim.x + threadIdx.x;
    if (i >= ET) return;
    int dv = (i < N_EDGES) ? ei[N_EDGES + i] : (i - N_EDGES);
    atomicAdd(&counts[dv], 1);
}

__global__ void scan1_k(const int* __restrict__ counts, int* __restrict__ offs,
                        int* __restrict__ bsums) {
    __shared__ int sm[512];
    int tid = threadIdx.x;
    int i = blockIdx.x * 512 + tid;
    int v = (i < N_NODES) ? counts[i] : 0;
    sm[tid] = v;
    __syncthreads();
    #pragma unroll
    for (int o = 1; o < 512; o <<= 1) {
        int add = (tid >= o) ? sm[tid - o] : 0;
        __syncthreads();
        sm[tid] += add;
        __syncthreads();
    }
    if (i < N_NODES) offs[i] = sm[tid] - v;        // exclusive
    if (tid == 511) bsums[blockIdx.x] = sm[511];
}

__global__ void scan2_k(int* __restrict__ bsums, int nb) {
    __shared__ int sm[128];
    int tid = threadIdx.x;
    int v = (tid < nb) ? bsums[tid] : 0;
    sm[tid] = v;
    __syncthreads();
    #pragma unroll
    for (int o = 1; o < 128; o <<= 1) {
        int add = (tid >= o) ? sm[tid - o] : 0;
        __syncthreads();
        sm[tid] += add;
        __syncthreads();
    }
    if (tid < nb) bsums[tid] = sm[tid] - v;        // exclusive
}

__global__ void scan3_k(int* __restrict__ offs, const int* __restrict__ bsums) {
    int i = blockIdx.x * 512 + threadIdx.x;
    if (i < N_NODES) offs[i] += bsums[blockIdx.x];
    if (i == 0) offs[N_NODES] = ET;
}

__global__ void fill_k(const int* __restrict__ ei, const int* __restrict__ offs,
                       int* __restrict__ cursor, int* __restrict__ csr) {
    int i = blockIdx.x * blockDim.x + threadIdx.x;
    if (i >= ET) return;
    int sv, dv;
    if (i < N_EDGES) { sv = ei[i]; dv = ei[N_EDGES + i]; }
    else             { sv = dv = i - N_EDGES; }
    int pos = offs[dv] + atomicAdd(&cursor[dv], 1);
    csr[pos] = sv;
}

// ------- GEMM (fp32 in, fp16 out; 128x64 tile, 256 thr, 8x4/thread) -------

__global__ __launch_bounds__(256) void gemm_k(const float* __restrict__ A,
                                              const float* __restrict__ B,
                                              __half* __restrict__ C,
                                              int N, int K, int Mout) {
    __shared__ float As[16][132];
    __shared__ float Bs[16][68];
    int t = threadIdx.x;
    int row0 = blockIdx.x * 128;
    int col0 = blockIdx.y * 64;
    int ty = t >> 4, tx = t & 15;     // ty: 8 rows each; tx: 4 cols each
    float acc[8][4];
    #pragma unroll
    for (int i = 0; i < 8; ++i)
        #pragma unroll
        for (int jj = 0; jj < 4; ++jj) acc[i][jj] = 0.f;

    int la_r = t >> 1;                // 0..127
    int la_k = (t & 1) * 8;           // 0 or 8
    int lb_k = t >> 4;                // 0..15
    int lb_n = (t & 15) * 4;          // 0..60

    for (int k0 = 0; k0 < K; k0 += 16) {
        float4 av0 = make_float4(0.f, 0.f, 0.f, 0.f);
        float4 av1 = make_float4(0.f, 0.f, 0.f, 0.f);
        int ar = row0 + la_r;
        if (ar < N) {
            const float* ap = A + (size_t)ar * K + k0 + la_k;
            av0 = *(const float4*)(ap);
            av1 = *(const float4*)(ap + 4);
        }
        float4 bv = *(const float4*)(B + (size_t)(k0 + lb_k) * Mout + col0 + lb_n);
        __syncthreads();
        As[la_k + 0][la_r] = av0.x; As[la_k + 1][la_r] = av0.y;
        As[la_k + 2][la_r] = av0.z; As[la_k + 3][la_r] = av0.w;
        As[la_k + 4][la_r] = av1.x; As[la_k + 5][la_r] = av1.y;
        As[la_k + 6][la_r] = av1.z; As[la_k + 7][la_r] = av1.w;
        *(float4*)&Bs[lb_k][lb_n] = bv;
        __syncthreads();
        #pragma unroll
        for (int kk = 0; kk < 16; ++kk) {
            float4 a0 = *(const float4*)&As[kk][ty * 8];
            float4 a1 = *(const float4*)&As[kk][ty * 8 + 4];
            float4 b  = *(const float4*)&Bs[kk][tx * 4];
            float ar_[8] = {a0.x, a0.y, a0.z, a0.w, a1.x, a1.y, a1.z, a1.w};
            float br_[4] = {b.x, b.y, b.z, b.w};
            #pragma unroll
            for (int i = 0; i < 8; ++i)
                #pragma unroll
                for (int jj = 0; jj < 4; ++jj)
                    acc[i][jj] += ar_[i] * br_[jj];
        }
    }
    #pragma unroll
    for (int i = 0; i < 8; ++i) {
        int r = row0 + ty * 8 + i;
        if (r < N) {
            union { __half2 h2[2]; float2 f2; } u;
            u.h2[0] = __floats2half2_rn(acc[i][0], acc[i][1]);
            u.h2[1] = __floats2half2_rn(acc[i][2], acc[i][3]);
            *(float2*)((__half*)C + (size_t)r * Mout + col0 + tx * 4) = u.f2;
        }
    }
}

// ---------------- per-node attention scores s,d ----------------

template<int H, int C>
__global__ __launch_bounds__(256) void scores_k(const __half* __restrict__ xp,
                                                const float* __restrict__ asrc,
                                                const float* __restrict__ adst,
                                                float* __restrict__ s,
                                                float* __restrict__ d) {
    constexpr int HCl = H * C;
    constexpr int EPL = HCl / 64;
    int wid = blockIdx.x * 4 + (threadIdx.x >> 6);
    int lane = threadIdx.x & 63;
    if (wid >= N_NODES) return;
    const __half* row = xp + (size_t)wid * HCl + lane * EPL;
    float v[EPL];
    if constexpr (EPL == 4) {
        union { float2 f2; __half2 h2[2]; } u;
        u.f2 = *(const float2*)row;
        float2 a = __half22float2(u.h2[0]);
        float2 b = __half22float2(u.h2[1]);
        v[0] = a.x; v[1] = a.y; v[2] = b.x; v[3] = b.y;
    } else {
        union { float f; __half2 h2; } u;
        u.f = *(const float*)row;
        float2 a = __half22float2(u.h2);
        v[0] = a.x; v[1] = a.y;
    }
    float ps = 0.f, pd = 0.f;
    #pragma unroll
    for (int k = 0; k < EPL; ++k) {
        ps += v[k] * asrc[lane * EPL + k];
        pd += v[k] * adst[lane * EPL + k];
    }
    constexpr int GW = 64 / H;
    #pragma unroll
    for (int o = 1; o < GW; o <<= 1) {
        ps += __shfl_xor(ps, o, 64);
        pd += __shfl_xor(pd, o, 64);
    }
    if ((lane & (GW - 1)) == 0) {
        int h = lane / GW;
        s[(size_t)wid * H + h] = ps;
        d[(size_t)wid * H + h] = pd;
    }
}

// ---------------- per-dst-node online-softmax aggregation ----------------

template<int H, int C, bool ELU_OUT>
__global__ __launch_bounds__(256) void aggr_k(const __half* __restrict__ xp,
                                              const float* __restrict__ s,
                                              const float* __restrict__ d,
                                              const int* __restrict__ offs,
                                              const int* __restrict__ csr,
                                              const float* __restrict__ bias,
                                              float* __restrict__ out) {
    constexpr int HCl = H * C;
    constexpr int EPL = HCl / 64;
    int wid = blockIdx.x * 4 + (threadIdx.x >> 6);
    int lane = threadIdx.x & 63;
    if (wid >= N_NODES) return;
    int h = (lane * EPL) / C;
    float dh = d[(size_t)wid * H + h];
    float m = -1e30f, z = 0.f;
    float acc[EPL];
    #pragma unroll
    for (int k = 0; k < EPL; ++k) acc[k] = 0.f;

    auto loadrow = [&](int src, float* v) {
        const __half* xr = xp + (size_t)src * HCl + lane * EPL;
        if constexpr (EPL == 4) {
            union { float2 f2; __half2 h2[2]; } u;
            u.f2 = *(const float2*)xr;
            float2 a = __half22float2(u.h2[0]);
            float2 b = __half22float2(u.h2[1]);
            v[0] = a.x; v[1] = a.y; v[2] = b.x; v[3] = b.y;
        } else {
            union { float f; __half2 h2; } u;
            u.f = *(const float*)xr;
            float2 a = __half22float2(u.h2);
            v[0] = a.x; v[1] = a.y;
        }
    };
    auto upd = [&](float ev, const float* v) {
        ev = (ev > 0.f) ? ev : 0.2f * ev;      // leaky_relu
        float mn = fmaxf(m, ev);
        float sc = __expf(m - mn);
        float p  = __expf(ev - mn);
        z = z * sc + p;
        #pragma unroll
        for (int k = 0; k < EPL; ++k) acc[k] = acc[k] * sc + p * v[k];
        m = mn;
    };

    int e0 = offs[wid], e1 = offs[wid + 1];
    int j = e0;
    for (; j + 4 <= e1; j += 4) {
        int s0 = csr[j], s1 = csr[j + 1], s2 = csr[j + 2], s3 = csr[j + 3];
        float E0 = s[(size_t)s0 * H + h] + dh;
        float E1 = s[(size_t)s1 * H + h] + dh;
        float E2 = s[(size_t)s2 * H + h] + dh;
        float E3 = s[(size_t)s3 * H + h] + dh;
        float v0[EPL], v1[EPL], v2[EPL], v3[EPL];
        loadrow(s0, v0); loadrow(s1, v1); loadrow(s2, v2); loadrow(s3, v3);
        upd(E0, v0); upd(E1, v1); upd(E2, v2); upd(E3, v3);
    }
    for (; j < e1; ++j) {
        int sv = csr[j];
        float E = s[(size_t)sv * H + h] + dh;
        float v[EPL];
        loadrow(sv, v);
        upd(E, v);
    }

    float inv = 1.f / (z + 1e-16f);
    #pragma unroll
    for (int k = 0; k < EPL; ++k) {
        float o = acc[k] * inv + bias[lane * EPL + k];
        if constexpr (ELU_OUT) o = (o > 0.f) ? o : (__expf(o) - 1.f);
        out[(size_t)wid * HCl + lane * EPL + k] = o;
    }
}

// ---------------- launch ----------------

extern "C" void kernel_launch(void* const* d_in, const int* in_sizes, int n_in,
                              void* d_out, int out_size, void* d_ws, size_t ws_size,
                              hipStream_t stream) {
    const float* x      = (const float*)d_in[0];
    const int*   ei     = (const int*)  d_in[1];
    const float* W0     = (const float*)d_in[2];
    const float* as0    = (const float*)d_in[3];
    const float* ad0    = (const float*)d_in[4];
    const float* b0     = (const float*)d_in[5];
    const float* W1     = (const float*)d_in[6];
    const float* as1    = (const float*)d_in[7];
    const float* ad1    = (const float*)d_in[8];
    const float* b1     = (const float*)d_in[9];
    const float* W2     = (const float*)d_in[10];
    const float* as2    = (const float*)d_in[11];
    const float* ad2    = (const float*)d_in[12];
    const float* b2     = (const float*)d_in[13];
    float* out = (float*)d_out;

    // workspace layout (256B aligned chunks)
    char* p = (char*)d_ws;
    auto take = [&](size_t bytes) {
        char* r = p;
        p += (bytes + 255) & ~(size_t)255;
        return r;
    };
    __half* XPh   = (__half*)take((size_t)N_NODES * HC * 2);
    float*  Hbuf  = (float*) take((size_t)N_NODES * HC * 4);
    float*  S     = (float*) take((size_t)N_NODES * HEADS * 4);
    float*  D     = (float*) take((size_t)N_NODES * HEADS * 4);
    int*    counts= (int*)   take((size_t)2 * N_NODES * 4);   // counts + cursor
    int*    cursor= counts + N_NODES;
    int*    offs  = (int*)   take((size_t)(N_NODES + 1) * 4);
    int*    bsums = (int*)   take(512 * 4);
    int*    csr   = (int*)   take((size_t)ET * 4);

    const int NB_SCAN = (N_NODES + 511) / 512;   // 98
    const int ET_BLOCKS = (ET + 255) / 256;
    const int NODE_BLOCKS = (N_NODES + 3) / 4;   // 12500

    // ---- CSR build ----
    hipMemsetAsync(counts, 0, (size_t)2 * N_NODES * 4, stream);
    hist_k<<<ET_BLOCKS, 256, 0, stream>>>(ei, counts);
    scan1_k<<<NB_SCAN, 512, 0, stream>>>(counts, offs, bsums);
    scan2_k<<<1, 128, 0, stream>>>(bsums, NB_SCAN);
    scan3_k<<<NB_SCAN, 512, 0, stream>>>(offs, bsums);
    fill_k<<<ET_BLOCKS, 256, 0, stream>>>(ei, offs, cursor, csr);

    dim3 g0((N_NODES + 127) / 128, HC / 64);
    dim3 g2((N_NODES + 127) / 128, OUTD / 64);

    // ---- layer 0: 128 -> 4x64, concat, ELU ----
    gemm_k<<<g0, 256, 0, stream>>>(x, W0, XPh, N_NODES, IN_DIM, HC);
    scores_k<HEADS, HID><<<NODE_BLOCKS, 256, 0, stream>>>(XPh, as0, ad0, S, D);
    aggr_k<HEADS, HID, true><<<NODE_BLOCKS, 256, 0, stream>>>(XPh, S, D, offs, csr, b0, Hbuf);

    // ---- layer 1: 256 -> 4x64, concat, ELU ----
    gemm_k<<<g0, 256, 0, stream>>>(Hbuf, W1, XPh, N_NODES, HC, HC);
    scores_k<HEADS, HID><<<NODE_BLOCKS, 256, 0, stream>>>(XPh, as1, ad1, S, D);
    aggr_k<HEADS, HID, true><<<NODE_BLOCKS, 256, 0, stream>>>(XPh, S, D, offs, csr, b1, Hbuf);

    // ---- layer 2: 256 -> 1x128, mean(H=1), no ELU ----
    gemm_k<<<g2, 256, 0, stream>>>(Hbuf, W2, XPh, N_NODES, HC, OUTD);
    scores_k<1, OUTD><<<NODE_BLOCKS, 256, 0, stream>>>(XPh, as2, ad2, S, D);
    aggr_k<1, OUTD, false><<<NODE_BLOCKS, 256, 0, stream>>>(XPh, S, D, offs, csr, b2, out);
}

// Round 3
// 448.683 us; speedup vs baseline: 1.7317x; 1.3223x over previous
//
#include <hip/hip_runtime.h>
#include <hip/hip_bf16.h>
#include <hip/hip_fp16.h>
#include <math.h>

#define N_NODES 50000
#define N_EDGES 800000
#define ET      (N_EDGES + N_NODES)   // with self loops
#define IN_DIM  128
#define HEADS   4
#define HID     64
#define HC      256                   // HEADS*HID
#define OUTD    128

typedef _Float16 half8 __attribute__((ext_vector_type(8)));
typedef float f32x4 __attribute__((ext_vector_type(4)));

// ---------------- CSR build ----------------

__global__ void hist_k(const int* __restrict__ ei, int* __restrict__ counts) {
    int i = blockIdx.x * blockDim.x + threadIdx.x;
    if (i >= ET) return;
    int dv = (i < N_EDGES) ? ei[N_EDGES + i] : (i - N_EDGES);
    atomicAdd(&counts[dv], 1);
}

__global__ void scan1_k(const int* __restrict__ counts, int* __restrict__ offs,
                        int* __restrict__ bsums) {
    __shared__ int sm[512];
    int tid = threadIdx.x;
    int i = blockIdx.x * 512 + tid;
    int v = (i < N_NODES) ? counts[i] : 0;
    sm[tid] = v;
    __syncthreads();
    #pragma unroll
    for (int o = 1; o < 512; o <<= 1) {
        int add = (tid >= o) ? sm[tid - o] : 0;
        __syncthreads();
        sm[tid] += add;
        __syncthreads();
    }
    if (i < N_NODES) offs[i] = sm[tid] - v;        // exclusive
    if (tid == 511) bsums[blockIdx.x] = sm[511];
}

__global__ void scan2_k(int* __restrict__ bsums, int nb) {
    __shared__ int sm[128];
    int tid = threadIdx.x;
    int v = (tid < nb) ? bsums[tid] : 0;
    sm[tid] = v;
    __syncthreads();
    #pragma unroll
    for (int o = 1; o < 128; o <<= 1) {
        int add = (tid >= o) ? sm[tid - o] : 0;
        __syncthreads();
        sm[tid] += add;
        __syncthreads();
    }
    if (tid < nb) bsums[tid] = sm[tid] - v;        // exclusive
}

__global__ void scan3_k(int* __restrict__ offs, const int* __restrict__ bsums) {
    int i = blockIdx.x * 512 + threadIdx.x;
    if (i < N_NODES) offs[i] += bsums[blockIdx.x];
    if (i == 0) offs[N_NODES] = ET;
}

__global__ void fill_k(const int* __restrict__ ei, const int* __restrict__ offs,
                       int* __restrict__ cursor, int* __restrict__ csr) {
    int i = blockIdx.x * blockDim.x + threadIdx.x;
    if (i >= ET) return;
    int sv, dv;
    if (i < N_EDGES) { sv = ei[i]; dv = ei[N_EDGES + i]; }
    else             { sv = dv = i - N_EDGES; }
    int pos = offs[dv] + atomicAdd(&cursor[dv], 1);
    csr[pos] = sv;
}

// ---------------- converts ----------------

__global__ void cvt_fp16_k(const float* __restrict__ x, __half* __restrict__ xh, int n4) {
    int i = blockIdx.x * 256 + threadIdx.x;
    if (i >= n4) return;
    float4 v = *(const float4*)(x + (size_t)i * 4);
    union { __half2 h2[2]; float2 f2; } u;
    u.h2[0] = __floats2half2_rn(v.x, v.y);
    u.h2[1] = __floats2half2_rn(v.z, v.w);
    *(float2*)(xh + (size_t)i * 4) = u.f2;
}

// Wt[n][k] = (half)W[k][n]
__global__ void wtrans_k(const float* __restrict__ W, __half* __restrict__ Wt, int K, int N) {
    int idx = blockIdx.x * 256 + threadIdx.x;
    if (idx >= K * N) return;
    int n = idx / K, k = idx - n * K;
    Wt[idx] = __float2half(W[(size_t)k * N + n]);
}

// ---------------- MFMA fp16 GEMM: C[M][N] = A[M][K] * Wt[N][K]^T ----------------
// 128x128 block tile, 4 waves (64x64 each), 16x16x32 f16 MFMA, BK=32.

__device__ __forceinline__ void async_copy16(void* lds_base, const void* gaddr) {
    __builtin_amdgcn_global_load_lds(
        (const __attribute__((address_space(1))) unsigned int*)gaddr,
        (__attribute__((address_space(3))) unsigned int*)lds_base,
        16, 0, 0);
}

__global__ __launch_bounds__(256) void gemm_mfma_k(const __half* __restrict__ A,
                                                   const __half* __restrict__ Wt,
                                                   __half* __restrict__ C,
                                                   int M, int K, int N) {
    __shared__ __attribute__((aligned(16))) __half Ah[128 * 32];
    __shared__ __attribute__((aligned(16))) __half Bh[128 * 32];
    const int t = threadIdx.x;
    const int w = t >> 6;            // wave 0..3 (uniform within wave)
    const int lane = t & 63;
    const int wm = w >> 1, wn = w & 1;
    const int row0 = blockIdx.x * 128;
    const int col0 = blockIdx.y * 128;

    f32x4 acc[4][4];
    #pragma unroll
    for (int i = 0; i < 4; ++i)
        #pragma unroll
        for (int j = 0; j < 4; ++j) acc[i][j] = (f32x4){0.f, 0.f, 0.f, 0.f};

    // staging: each global_load_lds covers 16 rows x 32 halfs (lane -> row=lane>>2, kq=lane&3)
    const int srow = lane >> 2;
    const int skq  = (lane & 3) * 8;
    const int fr = lane & 15;
    const int fq = (lane >> 4) * 8;

    for (int k0 = 0; k0 < K; k0 += 32) {
        __syncthreads();
        #pragma unroll
        for (int hh = 0; hh < 2; ++hh) {
            int ra = row0 + w * 32 + hh * 16 + srow;
            if (ra > M - 1) ra = M - 1;                    // clamp (results discarded)
            async_copy16(&Ah[(w * 32 + hh * 16) * 32],
                         A + (size_t)ra * K + k0 + skq);
            int rb = col0 + w * 32 + hh * 16 + srow;       // N multiple of 128
            async_copy16(&Bh[(w * 32 + hh * 16) * 32],
                         Wt + (size_t)rb * K + k0 + skq);
        }
        __syncthreads();
        half8 a[4], b[4];
        #pragma unroll
        for (int i = 0; i < 4; ++i)
            a[i] = *(const half8*)&Ah[(wm * 64 + i * 16 + fr) * 32 + fq];
        #pragma unroll
        for (int j = 0; j < 4; ++j)
            b[j] = *(const half8*)&Bh[(wn * 64 + j * 16 + fr) * 32 + fq];
        #pragma unroll
        for (int i = 0; i < 4; ++i)
            #pragma unroll
            for (int j = 0; j < 4; ++j)
                acc[i][j] = __builtin_amdgcn_mfma_f32_16x16x32_f16(a[i], b[j], acc[i][j], 0, 0, 0);
    }

    // epilogue: C/D layout col=lane&15, row=(lane>>4)*4+reg
    const int cr = (lane >> 4) * 4;
    const int cc = lane & 15;
    #pragma unroll
    for (int i = 0; i < 4; ++i) {
        #pragma unroll
        for (int j = 0; j < 4; ++j) {
            int c = col0 + wn * 64 + j * 16 + cc;
            #pragma unroll
            for (int reg = 0; reg < 4; ++reg) {
                int r = row0 + wm * 64 + i * 16 + cr + reg;
                if (r < M)
                    C[(size_t)r * N + c] = __float2half(acc[i][j][reg]);
            }
        }
    }
}

// ---------------- per-node attention scores s,d ----------------

template<int H, int C>
__global__ __launch_bounds__(256) void scores_k(const __half* __restrict__ xp,
                                                const float* __restrict__ asrc,
                                                const float* __restrict__ adst,
                                                float* __restrict__ s,
                                                float* __restrict__ d) {
    constexpr int HCl = H * C;
    constexpr int EPL = HCl / 64;
    int wid = blockIdx.x * 4 + (threadIdx.x >> 6);
    int lane = threadIdx.x & 63;
    if (wid >= N_NODES) return;
    const __half* row = xp + (size_t)wid * HCl + lane * EPL;
    float v[EPL];
    if constexpr (EPL == 4) {
        union { float2 f2; __half2 h2[2]; } u;
        u.f2 = *(const float2*)row;
        float2 a = __half22float2(u.h2[0]);
        float2 b = __half22float2(u.h2[1]);
        v[0] = a.x; v[1] = a.y; v[2] = b.x; v[3] = b.y;
    } else {
        union { float f; __half2 h2; } u;
        u.f = *(const float*)row;
        float2 a = __half22float2(u.h2);
        v[0] = a.x; v[1] = a.y;
    }
    float ps = 0.f, pd = 0.f;
    #pragma unroll
    for (int k = 0; k < EPL; ++k) {
        ps += v[k] * asrc[lane * EPL + k];
        pd += v[k] * adst[lane * EPL + k];
    }
    constexpr int GW = 64 / H;
    #pragma unroll
    for (int o = 1; o < GW; o <<= 1) {
        ps += __shfl_xor(ps, o, 64);
        pd += __shfl_xor(pd, o, 64);
    }
    if ((lane & (GW - 1)) == 0) {
        int h = lane / GW;
        s[(size_t)wid * H + h] = ps;
        d[(size_t)wid * H + h] = pd;
    }
}

// ---------------- per-dst-node online-softmax aggregation ----------------

template<int H, int C, bool ELU_OUT, typename OT>
__global__ __launch_bounds__(256) void aggr_k(const __half* __restrict__ xp,
                                              const float* __restrict__ s,
                                              const float* __restrict__ d,
                                              const int* __restrict__ offs,
                                              const int* __restrict__ csr,
                                              const float* __restrict__ bias,
                                              OT* __restrict__ out) {
    constexpr int HCl = H * C;
    constexpr int EPL = HCl / 64;
    int wid = blockIdx.x * 4 + (threadIdx.x >> 6);
    int lane = threadIdx.x & 63;
    if (wid >= N_NODES) return;
    int h = (lane * EPL) / C;
    float dh = d[(size_t)wid * H + h];
    float m = -1e30f, z = 0.f;
    float acc[EPL];
    #pragma unroll
    for (int k = 0; k < EPL; ++k) acc[k] = 0.f;

    auto loadrow = [&](int src, float* v) {
        const __half* xr = xp + (size_t)src * HCl + lane * EPL;
        if constexpr (EPL == 4) {
            union { float2 f2; __half2 h2[2]; } u;
            u.f2 = *(const float2*)xr;
            float2 a = __half22float2(u.h2[0]);
            float2 b = __half22float2(u.h2[1]);
            v[0] = a.x; v[1] = a.y; v[2] = b.x; v[3] = b.y;
        } else {
            union { float f; __half2 h2; } u;
            u.f = *(const float*)xr;
            float2 a = __half22float2(u.h2);
            v[0] = a.x; v[1] = a.y;
        }
    };
    auto upd = [&](float ev, const float* v) {
        ev = (ev > 0.f) ? ev : 0.2f * ev;      // leaky_relu
        float mn = fmaxf(m, ev);
        float sc = __expf(m - mn);
        float p  = __expf(ev - mn);
        z = z * sc + p;
        #pragma unroll
        for (int k = 0; k < EPL; ++k) acc[k] = acc[k] * sc + p * v[k];
        m = mn;
    };

    int e0 = offs[wid], e1 = offs[wid + 1];
    int j = e0;
    for (; j + 4 <= e1; j += 4) {
        int s0 = csr[j], s1 = csr[j + 1], s2 = csr[j + 2], s3 = csr[j + 3];
        float E0 = s[(size_t)s0 * H + h] + dh;
        float E1 = s[(size_t)s1 * H + h] + dh;
        float E2 = s[(size_t)s2 * H + h] + dh;
        float E3 = s[(size_t)s3 * H + h] + dh;
        float v0[EPL], v1[EPL], v2[EPL], v3[EPL];
        loadrow(s0, v0); loadrow(s1, v1); loadrow(s2, v2); loadrow(s3, v3);
        upd(E0, v0); upd(E1, v1); upd(E2, v2); upd(E3, v3);
    }
    for (; j < e1; ++j) {
        int sv = csr[j];
        float E = s[(size_t)sv * H + h] + dh;
        float v[EPL];
        loadrow(sv, v);
        upd(E, v);
    }

    float inv = 1.f / (z + 1e-16f);
    float o[EPL];
    #pragma unroll
    for (int k = 0; k < EPL; ++k) {
        o[k] = acc[k] * inv + bias[lane * EPL + k];
        if constexpr (ELU_OUT) o[k] = (o[k] > 0.f) ? o[k] : (__expf(o[k]) - 1.f);
    }
    if constexpr (sizeof(OT) == 2 && EPL == 4) {
        union { __half2 h2[2]; float2 f2; } u;
        u.h2[0] = __floats2half2_rn(o[0], o[1]);
        u.h2[1] = __floats2half2_rn(o[2], o[3]);
        *(float2*)((__half*)out + (size_t)wid * HCl + lane * EPL) = u.f2;
    } else {
        #pragma unroll
        for (int k = 0; k < EPL; ++k)
            out[(size_t)wid * HCl + lane * EPL + k] = (OT)o[k];
    }
}

// ---------------- launch ----------------

extern "C" void kernel_launch(void* const* d_in, const int* in_sizes, int n_in,
                              void* d_out, int out_size, void* d_ws, size_t ws_size,
                              hipStream_t stream) {
    const float* x      = (const float*)d_in[0];
    const int*   ei     = (const int*)  d_in[1];
    const float* W0     = (const float*)d_in[2];
    const float* as0    = (const float*)d_in[3];
    const float* ad0    = (const float*)d_in[4];
    const float* b0     = (const float*)d_in[5];
    const float* W1     = (const float*)d_in[6];
    const float* as1    = (const float*)d_in[7];
    const float* ad1    = (const float*)d_in[8];
    const float* b1     = (const float*)d_in[9];
    const float* W2     = (const float*)d_in[10];
    const float* as2    = (const float*)d_in[11];
    const float* ad2    = (const float*)d_in[12];
    const float* b2     = (const float*)d_in[13];
    float* out = (float*)d_out;

    // workspace layout (256B aligned chunks)
    char* p = (char*)d_ws;
    auto take = [&](size_t bytes) {
        char* r = p;
        p += (bytes + 255) & ~(size_t)255;
        return r;
    };
    __half* XPh   = (__half*)take((size_t)N_NODES * HC * 2);
    __half* Hbuf  = (__half*)take((size_t)N_NODES * HC * 2);
    __half* xh    = (__half*)take((size_t)N_NODES * IN_DIM * 2);
    __half* Wt0   = (__half*)take((size_t)IN_DIM * HC * 2);
    __half* Wt1   = (__half*)take((size_t)HC * HC * 2);
    __half* Wt2   = (__half*)take((size_t)HC * OUTD * 2);
    float*  S     = (float*) take((size_t)N_NODES * HEADS * 4);
    float*  D     = (float*) take((size_t)N_NODES * HEADS * 4);
    int*    counts= (int*)   take((size_t)2 * N_NODES * 4);   // counts + cursor
    int*    cursor= counts + N_NODES;
    int*    offs  = (int*)   take((size_t)(N_NODES + 1) * 4);
    int*    bsums = (int*)   take(512 * 4);
    int*    csr   = (int*)   take((size_t)ET * 4);

    const int NB_SCAN = (N_NODES + 511) / 512;   // 98
    const int ET_BLOCKS = (ET + 255) / 256;
    const int NODE_BLOCKS = (N_NODES + 3) / 4;   // 12500

    // ---- CSR build ----
    hipMemsetAsync(counts, 0, (size_t)2 * N_NODES * 4, stream);
    hist_k<<<ET_BLOCKS, 256, 0, stream>>>(ei, counts);
    scan1_k<<<NB_SCAN, 512, 0, stream>>>(counts, offs, bsums);
    scan2_k<<<1, 128, 0, stream>>>(bsums, NB_SCAN);
    scan3_k<<<NB_SCAN, 512, 0, stream>>>(offs, bsums);
    fill_k<<<ET_BLOCKS, 256, 0, stream>>>(ei, offs, cursor, csr);

    // ---- converts ----
    cvt_fp16_k<<<(N_NODES * IN_DIM / 4 + 255) / 256, 256, 0, stream>>>(x, xh, N_NODES * IN_DIM / 4);
    wtrans_k<<<(IN_DIM * HC + 255) / 256, 256, 0, stream>>>(W0, Wt0, IN_DIM, HC);
    wtrans_k<<<(HC * HC + 255) / 256, 256, 0, stream>>>(W1, Wt1, HC, HC);
    wtrans_k<<<(HC * OUTD + 255) / 256, 256, 0, stream>>>(W2, Wt2, HC, OUTD);

    const int MB = (N_NODES + 127) / 128;        // 391
    dim3 g0(MB, HC / 128);                       // 391 x 2
    dim3 g2(MB, OUTD / 128);                     // 391 x 1

    // ---- layer 0: 128 -> 4x64, concat, ELU ----
    gemm_mfma_k<<<g0, 256, 0, stream>>>(xh, Wt0, XPh, N_NODES, IN_DIM, HC);
    scores_k<HEADS, HID><<<NODE_BLOCKS, 256, 0, stream>>>(XPh, as0, ad0, S, D);
    aggr_k<HEADS, HID, true, __half><<<NODE_BLOCKS, 256, 0, stream>>>(XPh, S, D, offs, csr, b0, Hbuf);

    // ---- layer 1: 256 -> 4x64, concat, ELU ----
    gemm_mfma_k<<<g0, 256, 0, stream>>>(Hbuf, Wt1, XPh, N_NODES, HC, HC);
    scores_k<HEADS, HID><<<NODE_BLOCKS, 256, 0, stream>>>(XPh, as1, ad1, S, D);
    aggr_k<HEADS, HID, true, __half><<<NODE_BLOCKS, 256, 0, stream>>>(XPh, S, D, offs, csr, b1, Hbuf);

    // ---- layer 2: 256 -> 1x128, mean(H=1), no ELU ----
    gemm_mfma_k<<<g2, 256, 0, stream>>>(Hbuf, Wt2, XPh, N_NODES, HC, OUTD);
    scores_k<1, OUTD><<<NODE_BLOCKS, 256, 0, stream>>>(XPh, as2, ad2, S, D);
    aggr_k<1, OUTD, false, float><<<NODE_BLOCKS, 256, 0, stream>>>(XPh, S, D, offs, csr, b2, out);
}